// Round 1
// baseline (88.669 us; speedup 1.0000x reference)
//
#include <hip/hip_runtime.h>
#include <stdint.h>

#define HID 128

typedef __attribute__((ext_vector_type(8))) __bf16 bf16x8;
typedef __attribute__((ext_vector_type(4))) float floatx4;

// load 8 consecutive fp32 and convert to a bf16x8 fragment.
// Native __bf16 casts compile to v_cvt_pk_bf16_f32 (RNE) on gfx950 —
// ~4 VALU ops per 8 elements vs ~28 for the manual round-and-pack,
// and no address-taken stack array that could defeat SROA.
__device__ inline bf16x8 load_cvt8(const float* __restrict__ p) {
    floatx4 v0 = *(const floatx4*)(p);
    floatx4 v1 = *(const floatx4*)(p + 4);
    bf16x8 r;
    r[0] = (__bf16)v0[0]; r[1] = (__bf16)v0[1];
    r[2] = (__bf16)v0[2]; r[3] = (__bf16)v0[3];
    r[4] = (__bf16)v1[0]; r[5] = (__bf16)v1[1];
    r[6] = (__bf16)v1[2]; r[7] = (__bf16)v1[3];
    return r;
}

// One wave owns a 16-row x 32-col output tile. No LDS, no barriers.
// Fragments are read straight from global (fp32) and converted in-register.
__global__ __launch_bounds__(256, 4) void elem_update_kernel(
    const float* __restrict__ h_prev,
    const float* __restrict__ m_curr,
    const int* __restrict__ atom_types,
    const float* __restrict__ weight,
    float* __restrict__ out)
{
    const int tid  = threadIdx.x;
    const int lane = tid & 63;
    const int wave = tid >> 6;
    const int l15  = lane & 15;
    const int quad = lane >> 4;

    const int wg       = blockIdx.x * 4 + wave;  // global wave id
    const int row_tile = wg >> 2;                // 16-row tile index
    const int cq       = wg & 3;                 // column quarter (32 cols)
    const int r0       = row_tile * 16;
    const int c0       = cq * 32;

    // species of this wave's 16 rows (same value pattern in every quad)
    const int t = atom_types[r0 + l15];

    int s = 0;
    while (s < 16) {
        const int z = __shfl(t, s);                       // wave-uniform species
        unsigned long long neq = __ballot(t != z);
        unsigned bits = (unsigned)(neq & 0xFFFFull) & ~((1u << (s + 1)) - 1u);
        const int e = bits ? (int)__builtin_ctz(bits) : 16;   // segment [s,e)

        const float* __restrict__ Wz = weight + (size_t)z * HID * HID;

        // C-init = h_prev at the D-layout positions: row=quad*4+r, col=c0+nt*16+l15
        floatx4 acc[2];
        #pragma unroll
        for (int nt = 0; nt < 2; ++nt) {
            #pragma unroll
            for (int r = 0; r < 4; ++r) {
                acc[nt][r] = h_prev[(size_t)(r0 + quad * 4 + r) * HID + c0 + nt * 16 + l15];
            }
        }

        #pragma unroll
        for (int kk = 0; kk < 4; ++kk) {
            // A-frag: A[m=l15][k=kk*32+quad*8+j] = m_curr row (r0+l15)
            bf16x8 a = load_cvt8(m_curr + (size_t)(r0 + l15) * HID + kk * 32 + quad * 8);
            #pragma unroll
            for (int nt = 0; nt < 2; ++nt) {
                // B-frag: B[k][n=l15] = W[n][k] -> W row (c0+nt*16+l15)
                bf16x8 b = load_cvt8(Wz + (size_t)(c0 + nt * 16 + l15) * HID + kk * 32 + quad * 8);
                acc[nt] = __builtin_amdgcn_mfma_f32_16x16x32_bf16(a, b, acc[nt], 0, 0, 0);
            }
        }

        // epilogue: D[row=quad*4+r][col=c0+nt*16+l15], only rows in [s,e)
        #pragma unroll
        for (int nt = 0; nt < 2; ++nt) {
            #pragma unroll
            for (int r = 0; r < 4; ++r) {
                int row = quad * 4 + r;
                if (row >= s && row < e) {
                    size_t idx = (size_t)(r0 + row) * HID + c0 + nt * 16 + l15;
                    out[idx] = acc[nt][r];
                }
            }
        }
        s = e;
    }
}

extern "C" void kernel_launch(void* const* d_in, const int* in_sizes, int n_in,
                              void* d_out, int out_size, void* d_ws, size_t ws_size,
                              hipStream_t stream) {
    const float* h_prev     = (const float*)d_in[0];
    const float* m_curr     = (const float*)d_in[1];
    const int*   atom_types = (const int*)d_in[2];
    const float* weight     = (const float*)d_in[3];
    float*       out        = (float*)d_out;

    const int n_nodes = in_sizes[2];       // 16384
    const int blocks  = n_nodes / 16;      // 1024 blocks x 4 waves = 4096 waves
    elem_update_kernel<<<blocks, 256, 0, stream>>>(h_prev, m_curr, atom_types, weight, out);
}

// Round 2
// 79.096 us; speedup vs baseline: 1.1210x; 1.1210x over previous
//
#include <hip/hip_runtime.h>
#include <stdint.h>

#define HID 128

typedef __attribute__((ext_vector_type(8))) __bf16 bf16x8;
typedef __attribute__((ext_vector_type(4))) float floatx4;

// load 8 consecutive fp32 and convert to a bf16x8 fragment.
// Native __bf16 casts compile to v_cvt_pk_bf16_f32 (RNE) on gfx950.
__device__ inline bf16x8 load_cvt8(const float* __restrict__ p) {
    floatx4 v0 = *(const floatx4*)(p);
    floatx4 v1 = *(const floatx4*)(p + 4);
    bf16x8 r;
    r[0] = (__bf16)v0[0]; r[1] = (__bf16)v0[1];
    r[2] = (__bf16)v0[2]; r[3] = (__bf16)v0[3];
    r[4] = (__bf16)v1[0]; r[5] = (__bf16)v1[1];
    r[6] = (__bf16)v1[2]; r[7] = (__bf16)v1[3];
    return r;
}

// Block = 256 threads (4 waves) owns 64 rows x 128 cols.
// Wave w computes rows [blk+16w, blk+16w+16), ALL 128 columns (8 nt-tiles).
// Per species-segment (block-uniform, derived from sorted atom_types via
// ballot), W[z] (128x128 fp32) is cooperatively staged into LDS as bf16 with
// an XOR chunk-swizzle so the stride-256B ds_read_b128 B-fragment reads are
// bank-conflict-free (unswizzled they are 16-way conflicts).
//  - W global reads: fully coalesced float4, ~24 MB total (vs ~64 MB strided before)
//  - m_curr: read once per row (A-frags hoisted; was 4x)
__global__ __launch_bounds__(256, 2) void elem_update_kernel(
    const float* __restrict__ h_prev,
    const float* __restrict__ m_curr,
    const int* __restrict__ atom_types,
    const float* __restrict__ weight,
    float* __restrict__ out)
{
    __shared__ __attribute__((aligned(16))) unsigned short Wlds[HID * HID]; // bf16 payload, 32 KB

    const int tid  = threadIdx.x;
    const int lane = tid & 63;
    const int wave = tid >> 6;
    const int l15  = lane & 15;
    const int quad = lane >> 4;

    const int blk_r0 = blockIdx.x * 64;      // block's 64 rows
    const int wr0    = blk_r0 + wave * 16;   // wave's 16 rows

    // block's 64 species, lane-indexed (identical across the 4 waves ->
    // segment loop is block-uniform, barriers are safe)
    const int t = atom_types[blk_r0 + lane];

    // A-frags: lane's m_curr row = wr0 + l15, cols kk*32 + quad*8 (species-independent, hoist)
    bf16x8 a[4];
    #pragma unroll
    for (int kk = 0; kk < 4; ++kk)
        a[kk] = load_cvt8(m_curr + (size_t)(wr0 + l15) * HID + kk * 32 + quad * 8);

    int s = 0;
    while (s < 64) {
        const int z = __shfl(t, s);                      // block-uniform species
        unsigned long long neq = __ballot(t != z);
        unsigned long long bits = (s < 63) ? (neq & ~((2ull << s) - 1ull)) : 0ull;
        const int e = bits ? (int)__builtin_ctzll(bits) : 64;   // segment [s,e) in block rows

        // ---- stage W[z] -> LDS bf16, swizzled ----
        __syncthreads();   // previous segment's readers are done with Wlds
        const float* __restrict__ Wz = weight + (size_t)z * (HID * HID);
        #pragma unroll
        for (int i = 0; i < 8; ++i) {
            const int linear = i * 2048 + tid * 8;       // element index, 8 floats/thread/iter
            const int row = linear >> 7;
            const int col = linear & 127;                // multiple of 8
            bf16x8 b = load_cvt8(Wz + linear);           // coalesced float4 x2
            const int chunk = (col >> 3) ^ (row & 15);   // XOR swizzle on 16B chunks
            *(bf16x8*)((char*)Wlds + row * 256 + chunk * 16) = b;  // ds_write_b128
        }
        __syncthreads();

        // ---- compute: waves whose rows intersect [s,e) ----
        const int lo = (s > wave * 16) ? s : wave * 16;
        const int hi = (e < wave * 16 + 16) ? e : wave * 16 + 16;
        if (lo < hi) {
            // C-init = h_prev at D-layout positions: row = quad*4+r, col = nt*16+l15
            floatx4 acc[8];
            #pragma unroll
            for (int nt = 0; nt < 8; ++nt) {
                #pragma unroll
                for (int r = 0; r < 4; ++r) {
                    acc[nt][r] = h_prev[(size_t)(wr0 + quad * 4 + r) * HID + nt * 16 + l15];
                }
            }
            #pragma unroll
            for (int kk = 0; kk < 4; ++kk) {
                #pragma unroll
                for (int nt = 0; nt < 8; ++nt) {
                    // B[k][n=l15] = W[n][k]; W row = nt*16+l15, k-chunk = kk*4+quad, swizzled
                    const int chunk = (kk * 4 + quad) ^ l15;   // row&15 == l15 here
                    bf16x8 b = *(const bf16x8*)((const char*)Wlds +
                                                (nt * 16 + l15) * 256 + chunk * 16);
                    acc[nt] = __builtin_amdgcn_mfma_f32_16x16x32_bf16(a[kk], b, acc[nt], 0, 0, 0);
                }
            }
            // epilogue: store only rows inside the segment
            #pragma unroll
            for (int nt = 0; nt < 8; ++nt) {
                #pragma unroll
                for (int r = 0; r < 4; ++r) {
                    const int brow = wave * 16 + quad * 4 + r;   // block-relative row
                    if (brow >= lo && brow < hi) {
                        out[(size_t)(blk_r0 + brow) * HID + nt * 16 + l15] = acc[nt][r];
                    }
                }
            }
        }
        s = e;
    }
}

extern "C" void kernel_launch(void* const* d_in, const int* in_sizes, int n_in,
                              void* d_out, int out_size, void* d_ws, size_t ws_size,
                              hipStream_t stream) {
    const float* h_prev     = (const float*)d_in[0];
    const float* m_curr     = (const float*)d_in[1];
    const int*   atom_types = (const int*)d_in[2];
    const float* weight     = (const float*)d_in[3];
    float*       out        = (float*)d_out;

    const int n_nodes = in_sizes[2];       // 16384
    const int blocks  = n_nodes / 64;      // 256 blocks x 4 waves
    elem_update_kernel<<<blocks, 256, 0, stream>>>(h_prev, m_curr, atom_types, weight, out);
}